// Round 18
// baseline (528.457 us; speedup 1.0000x reference)
//
#include <hip/hip_runtime.h>
#include <hip/hip_bf16.h>

#define M_BATCH 65536
#define K_IN    1024
#define N_OUT   256
#define TAU     0.015f

// d_ws layout (shorts): xhi [65536][1024], xlo [65536][1024], wt [256][1024]
#define XLO_SOFF 67108864ULL
#define WT_SOFF  134217728ULL
#define WS_NEED  268959744ULL   // bytes

typedef __attribute__((ext_vector_type(8))) short short8;
typedef __attribute__((ext_vector_type(4))) short short4v;
typedef __attribute__((ext_vector_type(4))) float f32x4;

__device__ inline short f2bf(float f) {
    __hip_bfloat16 h = __float2bfloat16(f);
    return __builtin_bit_cast(short, h);
}
__device__ inline float bf2f(short s) {
    unsigned u = ((unsigned)(unsigned short)s) << 16;
    return __builtin_bit_cast(float, u);
}

// ---- x -> bf16 hi/lo, LINEAR layout (pure streaming; no swizzle needed:
// fragments are read straight from global, not via LDS) ----
__global__ __launch_bounds__(512) void presplit(const float* __restrict__ x,
                                                short* __restrict__ xhi,
                                                short* __restrict__ xlo) {
    const int stride = gridDim.x * 512;
    for (int idx = blockIdx.x * 512 + threadIdx.x; idx < M_BATCH * (K_IN / 4); idx += stride) {
        const float4 v = ((const float4*)x)[idx];
        short4v h, l;
        h.x = f2bf(v.x); l.x = f2bf(v.x - bf2f(h.x));
        h.y = f2bf(v.y); l.y = f2bf(v.y - bf2f(h.y));
        h.z = f2bf(v.z); l.z = f2bf(v.z - bf2f(h.z));
        h.w = f2bf(v.w); l.w = f2bf(v.w - bf2f(h.w));
        ((short4v*)xhi)[idx] = h;
        ((short4v*)xlo)[idx] = l;
    }
}

// ---- W -> bf16 (exact: ternary), linear ----
__global__ __launch_bounds__(512) void wconv(const float* __restrict__ w,
                                             short* __restrict__ wt) {
    const int idx = blockIdx.x * 512 + threadIdx.x;    // 65536 float4 total
    const float4 v = ((const float4*)w)[idx];
    short4v h;
    h.x = f2bf(v.x); h.y = f2bf(v.y); h.z = f2bf(v.z); h.w = f2bf(v.w);
    ((short4v*)wt)[idx] = h;
}

// ---- main: barrier-free, LDS-free MFMA GEMM with direct global->VGPR
// fragment loads. Block = 128x128 tile, 4 waves (2m x 2n); A-rows are
// wave-private so LDS staging was pure overhead. Fragment load pattern
// (row=l15, 64B of k per row) = 16 full 64B lines per instruction.
// B (W bf16, 512KB) is L2-resident; per-wave direct reads = 512MB L2 total.
// Fixup: wave-cooperative via __ballot - x/w f32 rows loaded coalesced into
// per-wave LDS, C3 chain (r8-verified: kc=512 panels, sequential f32 chain,
// cs=p0+p1) run from LDS broadcast reads. ~1us/cell vs ~13us divergent.
__global__ __launch_bounds__(256) void binlin_dir(const float* __restrict__ x,
                                                  const float* __restrict__ wf,
                                                  const short* __restrict__ xhi,
                                                  const short* __restrict__ xlo,
                                                  const short* __restrict__ wt,
                                                  const float* __restrict__ bias,
                                                  const float* __restrict__ sign,
                                                  float* __restrict__ out) {
    __shared__ __align__(16) float fix[4][2048];   // per-wave: x row | w row (f32)

    const int tid  = threadIdx.x;
    const int lane = tid & 63;
    const int wid  = tid >> 6;       // 4 waves: 2(m) x 2(n)
    const int wm   = wid >> 1;
    const int wn   = wid & 1;
    const int l15  = lane & 15;
    const int l4   = lane >> 4;

    // bijective XCD-chunk swizzle (1024 = 8 x 128): consecutive logicals are
    // the two n-halves of one m-panel -> same XCD -> x L2-dedup.
    const int bid     = blockIdx.x;
    const int logical = (bid & 7) * 128 + (bid >> 3);
    const int m0 = (logical >> 1) * 128;
    const int n0 = (logical & 1) * 128;

    const size_t abase = (size_t)(m0 + wm * 64 + l15) * K_IN + l4 * 8;
    const size_t bbase = (size_t)(n0 + wn * 64 + l15) * K_IN + l4 * 8;

    f32x4 acc[4][4];
#pragma unroll
    for (int i = 0; i < 4; ++i)
#pragma unroll
        for (int j = 0; j < 4; ++j) acc[i][j] = (f32x4){0.f, 0.f, 0.f, 0.f};

#pragma unroll 2
    for (int kt = 0; kt < 16; ++kt) {
#pragma unroll
        for (int kk = 0; kk < 2; ++kk) {
            const size_t ko = (size_t)kt * 64 + kk * 32;
            short8 bfr[4];
#pragma unroll
            for (int ni = 0; ni < 4; ++ni)
                bfr[ni] = *(const short8*)(wt + bbase + (size_t)ni * 16 * K_IN + ko);
#pragma unroll
            for (int mi = 0; mi < 4; ++mi) {
                const short8 ahi = *(const short8*)(xhi + abase + (size_t)mi * 16 * K_IN + ko);
                const short8 alo = *(const short8*)(xlo + abase + (size_t)mi * 16 * K_IN + ko);
#pragma unroll
                for (int ni = 0; ni < 4; ++ni) {
                    acc[mi][ni] = __builtin_amdgcn_mfma_f32_16x16x32_bf16(
                        ahi, bfr[ni], acc[mi][ni], 0, 0, 0);
                    acc[mi][ni] = __builtin_amdgcn_mfma_f32_16x16x32_bf16(
                        alo, bfr[ni], acc[mi][ni], 0, 0, 0);
                }
            }
        }
    }

    // ---- epilogue: decide + wave-cooperative C3 fixup + direct stores
    // (store inst = 4 rows x 16 consecutive cols x 4B = 4 full 64B lines;
    //  each line written exactly once by one wave -> no amplification)
    float* fx = fix[wid];          // 1024 f32: x row
    float* fw = fix[wid] + 1024;   // 1024 f32: w row

#pragma unroll
    for (int ni = 0; ni < 4; ++ni) {
        const int n = n0 + wn * 64 + ni * 16 + l15;
        const float b = bias[n];
        const float s = sign[n];
#pragma unroll
        for (int mi = 0; mi < 4; ++mi) {
#pragma unroll
            for (int j = 0; j < 4; ++j) {
                const int m = m0 + wm * 64 + mi * 16 + l4 * 4 + j;
                const float t = (acc[mi][ni][j] + b) * s;
                float d = (t >= -0.5f) ? 1.0f : 0.0f;

                unsigned long long mask = __ballot(fabsf(t + 0.5f) < TAU);
                while (mask) {                       // wave-uniform loop
                    const int src = __ffsll(mask) - 1;
                    mask &= mask - 1;
                    const int mm = __shfl(m, src);
                    const int nn = __shfl(n, src);
                    // cooperative coalesced load of both f32 rows into LDS
                    const float4* xsrc = (const float4*)(x  + (size_t)mm * K_IN);
                    const float4* wsrc = (const float4*)(wf + (size_t)nn * K_IN);
#pragma unroll
                    for (int q = 0; q < 4; ++q) {
                        ((float4*)fx)[q * 64 + lane] = xsrc[q * 64 + lane];
                        ((float4*)fw)[q * 64 + lane] = wsrc[q * 64 + lane];
                    }
                    asm volatile("s_waitcnt vmcnt(0) lgkmcnt(0)" ::: "memory");
                    // C3-exact chain from LDS broadcasts (all lanes redundant)
                    float a0 = 0.f, a1 = 0.f;
                    for (int k4 = 0; k4 < 128; ++k4) {
                        const float4 xv0 = ((const float4*)fx)[k4];
                        const float4 wv0 = ((const float4*)fw)[k4];
                        const float4 xv1 = ((const float4*)fx)[128 + k4];
                        const float4 wv1 = ((const float4*)fw)[128 + k4];
                        a0 = fmaf(xv0.x, wv0.x, a0); a1 = fmaf(xv1.x, wv1.x, a1);
                        a0 = fmaf(xv0.y, wv0.y, a0); a1 = fmaf(xv1.y, wv1.y, a1);
                        a0 = fmaf(xv0.z, wv0.z, a0); a1 = fmaf(xv1.z, wv1.z, a1);
                        a0 = fmaf(xv0.w, wv0.w, a0); a1 = fmaf(xv1.w, wv1.w, a1);
                    }
                    const float tt = ((a0 + a1) + bias[nn]) * sign[nn];
                    const float dd = (tt >= -0.5f) ? 1.0f : 0.0f;
                    if (lane == src) d = dd;
                }
                out[(size_t)m * N_OUT + n] = d;
            }
        }
    }
}

// ---- fallback (r9-proven): fp32 tiled GEMM + C3 band fixup ----
__global__ __launch_bounds__(256) void binlin_fast(const float* __restrict__ x,
                                                   const float* __restrict__ w,
                                                   const float* __restrict__ bias,
                                                   const float* __restrict__ sign,
                                                   float* __restrict__ out) {
    __shared__ float As[32][132];
    __shared__ float Bs2[32][132];
    const int tid = threadIdx.x;
    const int tx  = tid & 15;
    const int ty  = tid >> 4;
    const int n0  = blockIdx.x * 128;
    const int m0  = blockIdx.y * 128;
    const int sr  = tid >> 3;
    const int sc  = (tid & 7) * 4;
    float acc[8][8];
#pragma unroll
    for (int i = 0; i < 8; ++i)
#pragma unroll
        for (int j = 0; j < 8; ++j) acc[i][j] = 0.f;
    for (int kt = 0; kt < K_IN; kt += 32) {
        __syncthreads();
#pragma unroll
        for (int q = 0; q < 4; ++q) {
            const int row = sr + q * 32;
            const float4 va = *(const float4*)(x + (size_t)(m0 + row) * K_IN + kt + sc);
            As[sc + 0][row] = va.x; As[sc + 1][row] = va.y;
            As[sc + 2][row] = va.z; As[sc + 3][row] = va.w;
            const float4 vb = *(const float4*)(w + (size_t)(n0 + row) * K_IN + kt + sc);
            Bs2[sc + 0][row] = vb.x; Bs2[sc + 1][row] = vb.y;
            Bs2[sc + 2][row] = vb.z; Bs2[sc + 3][row] = vb.w;
        }
        __syncthreads();
#pragma unroll
        for (int kk = 0; kk < 32; ++kk) {
            const float4 a0 = *(const float4*)&As[kk][ty * 8];
            const float4 a1 = *(const float4*)&As[kk][ty * 8 + 4];
            const float4 b0 = *(const float4*)&Bs2[kk][tx * 8];
            const float4 b1 = *(const float4*)&Bs2[kk][tx * 8 + 4];
            const float a[8] = {a0.x, a0.y, a0.z, a0.w, a1.x, a1.y, a1.z, a1.w};
            const float b[8] = {b0.x, b0.y, b0.z, b0.w, b1.x, b1.y, b1.z, b1.w};
#pragma unroll
            for (int i = 0; i < 8; ++i)
#pragma unroll
                for (int j = 0; j < 8; ++j)
                    acc[i][j] = fmaf(a[i], b[j], acc[i][j]);
        }
    }
    const int nb = n0 + tx * 8;
    float bv[8], sv[8];
#pragma unroll
    for (int j = 0; j < 8; ++j) { bv[j] = bias[nb + j]; sv[j] = sign[nb + j]; }
#pragma unroll
    for (int i = 0; i < 8; ++i) {
        const int m = m0 + ty * 8 + i;
        float o[8];
#pragma unroll
        for (int j = 0; j < 8; ++j) {
            const float t = (acc[i][j] + bv[j]) * sv[j];
            if (fabsf(t + 0.5f) < TAU) {
                const float* xr = x + (size_t)m * K_IN;
                const float* wr = w + (size_t)(nb + j) * K_IN;
                float cs = 0.f;
                for (int p = 0; p < 2; ++p) {
                    float a = 0.f;
                    const int kb = p * 512;
                    for (int k4 = 0; k4 < 128; ++k4) {
                        const float4 xv = *(const float4*)(xr + kb + k4 * 4);
                        const float4 wv = *(const float4*)(wr + kb + k4 * 4);
                        a = fmaf(xv.x, wv.x, a); a = fmaf(xv.y, wv.y, a);
                        a = fmaf(xv.z, wv.z, a); a = fmaf(xv.w, wv.w, a);
                    }
                    cs += a;
                }
                o[j] = (((cs + bv[j]) * sv[j]) >= -0.5f) ? 1.0f : 0.0f;
            } else {
                o[j] = (t >= -0.5f) ? 1.0f : 0.0f;
            }
        }
        float4* op = (float4*)(out + (size_t)m * N_OUT + nb);
        op[0] = make_float4(o[0], o[1], o[2], o[3]);
        op[1] = make_float4(o[4], o[5], o[6], o[7]);
    }
}

extern "C" void kernel_launch(void* const* d_in, const int* in_sizes, int n_in,
                              void* d_out, int out_size, void* d_ws, size_t ws_size,
                              hipStream_t stream) {
    const float* x    = (const float*)d_in[0];
    const float* w    = (const float*)d_in[1];
    const float* bias = (const float*)d_in[2];
    const float* sign = (const float*)d_in[3];

    if (n_in >= 4 && in_sizes[0] != M_BATCH * K_IN) {   // defensive no-op
        const float* small[2] = {nullptr, nullptr};
        int nsmall = 0;
        for (int i = 0; i < 4; ++i) {
            if (in_sizes[i] == M_BATCH * K_IN)      x = (const float*)d_in[i];
            else if (in_sizes[i] == N_OUT * K_IN)   w = (const float*)d_in[i];
            else if (nsmall < 2) small[nsmall++] = (const float*)d_in[i];
        }
        if (nsmall == 2) { bias = small[0]; sign = small[1]; }
    }

    float* out = (float*)d_out;

    if (ws_size >= WS_NEED) {
        short* xhi = (short*)d_ws;
        short* xlo = xhi + XLO_SOFF;
        short* wtp = xhi + WT_SOFF;
        presplit<<<2048, 512, 0, stream>>>(x, xhi, xlo);
        wconv<<<128, 512, 0, stream>>>(w, wtp);
        binlin_dir<<<1024, 256, 0, stream>>>(x, w, xhi, xlo, wtp, bias, sign, out);
    } else {
        dim3 grid(N_OUT / 128, M_BATCH / 128);
        binlin_fast<<<grid, 256, 0, stream>>>(x, w, bias, sign, out);
    }
}

// Round 19
// 418.319 us; speedup vs baseline: 1.2633x; 1.2633x over previous
//
#include <hip/hip_runtime.h>
#include <hip/hip_bf16.h>

#define M_BATCH 65536
#define K_IN    1024
#define N_OUT   256
#define TAU     0.015f

// d_ws layout (shorts): xhi [65536][1024], xlo [65536][1024], wt [256][1024]
#define XLO_SOFF 67108864ULL
#define WT_SOFF  134217728ULL
#define WS_NEED  268959744ULL   // bytes (exactly what rounds 14-18 proved available)

typedef __attribute__((ext_vector_type(8))) short short8;
typedef __attribute__((ext_vector_type(4))) short short4v;
typedef __attribute__((ext_vector_type(4))) float f32x4;

__device__ inline short f2bf(float f) {
    __hip_bfloat16 h = __float2bfloat16(f);
    return __builtin_bit_cast(short, h);
}
__device__ inline float bf2f(short s) {
    unsigned u = ((unsigned)(unsigned short)s) << 16;
    return __builtin_bit_cast(float, u);
}
__device__ inline void gload16(const void* g, void* lds) {
    __builtin_amdgcn_global_load_lds(
        (const __attribute__((address_space(1))) unsigned int*)g,
        (__attribute__((address_space(3))) unsigned int*)lds, 16, 0, 0);
}

// Swizzled destination offset (shorts): within each 64-k block, 16B cell c
// stored at c ^ (row & 7) (rule #21; r16/r17-verified end-to-end).
__device__ inline size_t swz_dst(int row, int col4 /*float4 idx*/) {
    const int kb = col4 >> 4;
    const int c  = (col4 >> 1) & 7;
    const int h  = col4 & 1;
    return (size_t)row * K_IN + kb * 64 + ((c ^ (row & 7)) << 3) + h * 4;
}

// ---- x -> bf16 hi/lo, swizzled layout ----
__global__ __launch_bounds__(512) void presplit19(const float* __restrict__ x,
                                                  short* __restrict__ xhi,
                                                  short* __restrict__ xlo) {
    const int stride = gridDim.x * 512;
    for (int idx = blockIdx.x * 512 + threadIdx.x; idx < M_BATCH * (K_IN / 4); idx += stride) {
        const int row  = idx >> 8;
        const int col4 = idx & 255;
        const float4 v = ((const float4*)x)[idx];
        short4v h, l;
        h.x = f2bf(v.x); l.x = f2bf(v.x - bf2f(h.x));
        h.y = f2bf(v.y); l.y = f2bf(v.y - bf2f(h.y));
        h.z = f2bf(v.z); l.z = f2bf(v.z - bf2f(h.z));
        h.w = f2bf(v.w); l.w = f2bf(v.w - bf2f(h.w));
        const size_t dst = swz_dst(row, col4);
        *(short4v*)(xhi + dst) = h;
        *(short4v*)(xlo + dst) = l;
    }
}

// ---- W -> bf16 (exact: ternary), swizzled ----
__global__ __launch_bounds__(512) void wconv19(const float* __restrict__ w,
                                               short* __restrict__ wt) {
    const int idx  = blockIdx.x * 512 + threadIdx.x;   // 65536 float4 total
    const int row  = idx >> 8;
    const int col4 = idx & 255;
    const float4 v = ((const float4*)w)[idx];
    short4v h;
    h.x = f2bf(v.x); h.y = f2bf(v.y); h.z = f2bf(v.z); h.w = f2bf(v.w);
    *(short4v*)(wt + swz_dst(row, col4)) = h;
}

// ---- PROBE: staging-only (gload_lds + barriers, no ds_read/MFMA).
// Mirrors K1's staging/barrier structure exactly. Times the barrier-locked
// staging pipeline in isolation (rule #17: LDS kept live via final read).
__global__ __launch_bounds__(256) void p_load19(const short* __restrict__ xhi,
                                                const short* __restrict__ xlo,
                                                const short* __restrict__ wt,
                                                int* __restrict__ sink) {
    __shared__ __align__(16) short smem[24576];
    const int tid  = threadIdx.x;
    const int lane = tid & 63;
    const int wid  = tid >> 6;
    const int bid     = blockIdx.x;
    const int logical = (bid & 7) * 128 + (bid >> 3);
    const int m0 = (logical >> 1) * 128;
    const int n0 = (logical & 1) * 128;
    const int srow = wid * 32 + (lane >> 3);
    const int scol = (lane & 7) * 8;
    const size_t asrc = (size_t)(m0 + srow) * K_IN + scol;
    const size_t bsrc = (size_t)(n0 + srow) * K_IN + scol;
    short* Ah = smem;
    short* Al = smem + 8192;
    short* Bs = smem + 16384;

    for (int kt = 0; kt < 16; ++kt) {
        __syncthreads();
#pragma unroll
        for (int q = 0; q < 4; ++q) {
            gload16(xhi + asrc + (size_t)q * 8 * K_IN + kt * 64, Ah + (wid * 32 + q * 8) * 64);
            gload16(xlo + asrc + (size_t)q * 8 * K_IN + kt * 64, Al + (wid * 32 + q * 8) * 64);
            gload16(wt  + bsrc + (size_t)q * 8 * K_IN + kt * 64, Bs + (wid * 32 + q * 8) * 64);
        }
        __syncthreads();
        asm volatile("" ::: "memory");
    }
    sink[bid * 256 + tid] = (int)smem[tid];   // keep staged data live
}

// ---- K1: r17's m97-structure GEMM, fixup REPLACED by sentinel (d = 2).
// Its rocprof row = GEMM + decide + store, zero fixup.
__global__ __launch_bounds__(256) void binlin_g19(const short* __restrict__ xhi,
                                                  const short* __restrict__ xlo,
                                                  const short* __restrict__ wt,
                                                  const float* __restrict__ bias,
                                                  const float* __restrict__ sign,
                                                  float* __restrict__ out) {
    __shared__ __align__(16) short smem[24576];   // Ah 8K | Al 8K | B 8K shorts

    const int bid     = blockIdx.x;                 // 0..1023
    const int logical = (bid & 7) * 128 + (bid >> 3);
    const int m0 = (logical >> 1) * 128;
    const int n0 = (logical & 1) * 128;

    const int tid  = threadIdx.x;
    const int lane = tid & 63;
    const int wid  = tid >> 6;       // 4 waves: 2(m) x 2(n)
    const int wm   = wid >> 1;
    const int wn   = wid & 1;
    const int l15  = lane & 15;
    const int l4   = lane >> 4;

    const int srow = wid * 32 + (lane >> 3);
    const int scol = (lane & 7) * 8;
    const size_t asrc = (size_t)(m0 + srow) * K_IN + scol;
    const size_t bsrc = (size_t)(n0 + srow) * K_IN + scol;

    f32x4 acc[4][4];
#pragma unroll
    for (int i = 0; i < 4; ++i)
#pragma unroll
        for (int j = 0; j < 4; ++j) acc[i][j] = (f32x4){0.f, 0.f, 0.f, 0.f};

    short* Ah = smem;
    short* Al = smem + 8192;
    short* Bs = smem + 16384;

    for (int kt = 0; kt < 16; ++kt) {
        __syncthreads();
#pragma unroll
        for (int q = 0; q < 4; ++q) {
            gload16(xhi + asrc + (size_t)q * 8 * K_IN + kt * 64, Ah + (wid * 32 + q * 8) * 64);
            gload16(xlo + asrc + (size_t)q * 8 * K_IN + kt * 64, Al + (wid * 32 + q * 8) * 64);
            gload16(wt  + bsrc + (size_t)q * 8 * K_IN + kt * 64, Bs + (wid * 32 + q * 8) * 64);
        }
        __syncthreads();

#pragma unroll
        for (int kk = 0; kk < 2; ++kk) {
            short8 bfr[4];
#pragma unroll
            for (int ni = 0; ni < 4; ++ni) {
                const int Rn = wn * 64 + ni * 16 + l15;
                bfr[ni] = *(const short8*)&Bs[Rn * 64 + (((kk * 4 + l4) ^ (Rn & 7)) << 3)];
            }
#pragma unroll
            for (int mi = 0; mi < 4; ++mi) {
                const int Rm  = wm * 64 + mi * 16 + l15;
                const int off = Rm * 64 + (((kk * 4 + l4) ^ (Rm & 7)) << 3);
                const short8 ahi = *(const short8*)&Ah[off];
                const short8 alo = *(const short8*)&Al[off];
#pragma unroll
                for (int ni = 0; ni < 4; ++ni) {
                    acc[mi][ni] = __builtin_amdgcn_mfma_f32_16x16x32_bf16(
                        ahi, bfr[ni], acc[mi][ni], 0, 0, 0);
                    acc[mi][ni] = __builtin_amdgcn_mfma_f32_16x16x32_bf16(
                        alo, bfr[ni], acc[mi][ni], 0, 0, 0);
                }
            }
        }
    }
    __syncthreads();

    // epilogue: decide; band cells get SENTINEL 2 (fixed by fixscan19)
    unsigned char* dec = (unsigned char*)smem;      // 16 KB overlay [128][128]
#pragma unroll
    for (int ni = 0; ni < 4; ++ni) {
        const int nl = wn * 64 + ni * 16 + l15;
        const int n  = n0 + nl;
        const float b = bias[n];
        const float s = sign[n];
#pragma unroll
        for (int mi = 0; mi < 4; ++mi) {
            const int ml = wm * 64 + mi * 16 + l4 * 4;
#pragma unroll
            for (int j = 0; j < 4; ++j) {
                const float t = (acc[mi][ni][j] + b) * s;
                unsigned char d;
                if (fabsf(t + 0.5f) < TAU) d = 2;
                else                       d = (t >= -0.5f) ? 1 : 0;
                dec[(ml + j) * 128 + nl] = d;
            }
        }
    }
    __syncthreads();

#pragma unroll
    for (int it = 0; it < 16; ++it) {
        const int f   = it * 256 + tid;   // float4 index in 128x128 tile
        const int row = f >> 5;
        const int c4  = f & 31;
        const uchar4 dv = *(const uchar4*)&dec[row * 128 + c4 * 4];
        *(float4*)(out + (size_t)(m0 + row) * N_OUT + n0 + c4 * 4) =
            make_float4((float)dv.x, (float)dv.y, (float)dv.z, (float)dv.w);
    }
}

// ---- K2: scan out for sentinel 2.0, fix with C3-exact chain
// (r8-verified ordering: kc=512 panels, one sequential f32 chain each).
// All 64 lanes run the chain redundantly on UNIFORM addresses (single-line
// broadcast loads), loads pipelined 1-ahead (r17's pattern).
__global__ __launch_bounds__(256) void fixscan19(const float* __restrict__ x,
                                                 const float* __restrict__ wf,
                                                 const float* __restrict__ bias,
                                                 const float* __restrict__ sign,
                                                 float* __restrict__ out) {
    const int lane = threadIdx.x & 63;
    const int wix  = blockIdx.x * 4 + (threadIdx.x >> 6);
    const long long nW    = (long long)gridDim.x * 4;
    const long long total = (long long)M_BATCH * N_OUT;

    for (long long base = (long long)wix * 64; base < total; base += nW * 64) {
        const float o = out[base + lane];
        unsigned long long mask = __ballot(o == 2.0f);
        while (mask) {
            const int src = __ffsll(mask) - 1;
            mask &= mask - 1;
            const long long f = base + src;
            const int m = (int)(f >> 8);
            const int n = (int)(f & 255);

            const float* xr_ = x  + (size_t)m * K_IN;
            const float* wr_ = wf + (size_t)n * K_IN;
            float a0 = 0.f, a1 = 0.f;
            float4 xc0 = *(const float4*)(xr_);
            float4 wc0 = *(const float4*)(wr_);
            float4 xc1 = *(const float4*)(xr_ + 512);
            float4 wc1 = *(const float4*)(wr_ + 512);
            for (int k4 = 0; k4 < 128; ++k4) {
                const int kn = (k4 + 1) & 127;
                const float4 nx0 = *(const float4*)(xr_ + kn * 4);
                const float4 nw0 = *(const float4*)(wr_ + kn * 4);
                const float4 nx1 = *(const float4*)(xr_ + 512 + kn * 4);
                const float4 nw1 = *(const float4*)(wr_ + 512 + kn * 4);
                a0 = fmaf(xc0.x, wc0.x, a0); a1 = fmaf(xc1.x, wc1.x, a1);
                a0 = fmaf(xc0.y, wc0.y, a0); a1 = fmaf(xc1.y, wc1.y, a1);
                a0 = fmaf(xc0.z, wc0.z, a0); a1 = fmaf(xc1.z, wc1.z, a1);
                a0 = fmaf(xc0.w, wc0.w, a0); a1 = fmaf(xc1.w, wc1.w, a1);
                xc0 = nx0; wc0 = nw0; xc1 = nx1; wc1 = nw1;
            }
            const float tt = ((a0 + a1) + bias[n]) * sign[n];
            if (lane == src) out[f] = (tt >= -0.5f) ? 1.0f : 0.0f;
        }
    }
}

// ---- fallback (r9-proven): fp32 tiled GEMM + inline C3 band fixup ----
__global__ __launch_bounds__(256) void binlin_fast(const float* __restrict__ x,
                                                   const float* __restrict__ w,
                                                   const float* __restrict__ bias,
                                                   const float* __restrict__ sign,
                                                   float* __restrict__ out) {
    __shared__ float As[32][132];
    __shared__ float Bs2[32][132];
    const int tid = threadIdx.x;
    const int tx  = tid & 15;
    const int ty  = tid >> 4;
    const int n0  = blockIdx.x * 128;
    const int m0  = blockIdx.y * 128;
    const int sr  = tid >> 3;
    const int sc  = (tid & 7) * 4;
    float acc[8][8];
#pragma unroll
    for (int i = 0; i < 8; ++i)
#pragma unroll
        for (int j = 0; j < 8; ++j) acc[i][j] = 0.f;
    for (int kt = 0; kt < K_IN; kt += 32) {
        __syncthreads();
#pragma unroll
        for (int q = 0; q < 4; ++q) {
            const int row = sr + q * 32;
            const float4 va = *(const float4*)(x + (size_t)(m0 + row) * K_IN + kt + sc);
            As[sc + 0][row] = va.x; As[sc + 1][row] = va.y;
            As[sc + 2][row] = va.z; As[sc + 3][row] = va.w;
            const float4 vb = *(const float4*)(w + (size_t)(n0 + row) * K_IN + kt + sc);
            Bs2[sc + 0][row] = vb.x; Bs2[sc + 1][row] = vb.y;
            Bs2[sc + 2][row] = vb.z; Bs2[sc + 3][row] = vb.w;
        }
        __syncthreads();
#pragma unroll
        for (int kk = 0; kk < 32; ++kk) {
            const float4 a0 = *(const float4*)&As[kk][ty * 8];
            const float4 a1 = *(const float4*)&As[kk][ty * 8 + 4];
            const float4 b0 = *(const float4*)&Bs2[kk][tx * 8];
            const float4 b1 = *(const float4*)&Bs2[kk][tx * 8 + 4];
            const float a[8] = {a0.x, a0.y, a0.z, a0.w, a1.x, a1.y, a1.z, a1.w};
            const float b[8] = {b0.x, b0.y, b0.z, b0.w, b1.x, b1.y, b1.z, b1.w};
#pragma unroll
            for (int i = 0; i < 8; ++i)
#pragma unroll
                for (int j = 0; j < 8; ++j)
                    acc[i][j] = fmaf(a[i], b[j], acc[i][j]);
        }
    }
    const int nb = n0 + tx * 8;
    float bv[8], sv[8];
#pragma unroll
    for (int j = 0; j < 8; ++j) { bv[j] = bias[nb + j]; sv[j] = sign[nb + j]; }
#pragma unroll
    for (int i = 0; i < 8; ++i) {
        const int m = m0 + ty * 8 + i;
        float o[8];
#pragma unroll
        for (int j = 0; j < 8; ++j) {
            const float t = (acc[i][j] + bv[j]) * sv[j];
            if (fabsf(t + 0.5f) < TAU) {
                const float* xr = x + (size_t)m * K_IN;
                const float* wr = w + (size_t)(nb + j) * K_IN;
                float cs = 0.f;
                for (int p = 0; p < 2; ++p) {
                    float a = 0.f;
                    const int kb = p * 512;
                    for (int k4 = 0; k4 < 128; ++k4) {
                        const float4 xv = *(const float4*)(xr + kb + k4 * 4);
                        const float4 wv = *(const float4*)(wr + kb + k4 * 4);
                        a = fmaf(xv.x, wv.x, a); a = fmaf(xv.y, wv.y, a);
                        a = fmaf(xv.z, wv.z, a); a = fmaf(xv.w, wv.w, a);
                    }
                    cs += a;
                }
                o[j] = (((cs + bv[j]) * sv[j]) >= -0.5f) ? 1.0f : 0.0f;
            } else {
                o[j] = (t >= -0.5f) ? 1.0f : 0.0f;
            }
        }
        float4* op = (float4*)(out + (size_t)m * N_OUT + nb);
        op[0] = make_float4(o[0], o[1], o[2], o[3]);
        op[1] = make_float4(o[4], o[5], o[6], o[7]);
    }
}

extern "C" void kernel_launch(void* const* d_in, const int* in_sizes, int n_in,
                              void* d_out, int out_size, void* d_ws, size_t ws_size,
                              hipStream_t stream) {
    const float* x    = (const float*)d_in[0];
    const float* w    = (const float*)d_in[1];
    const float* bias = (const float*)d_in[2];
    const float* sign = (const float*)d_in[3];

    if (n_in >= 4 && in_sizes[0] != M_BATCH * K_IN) {   // defensive no-op
        const float* small[2] = {nullptr, nullptr};
        int nsmall = 0;
        for (int i = 0; i < 4; ++i) {
            if (in_sizes[i] == M_BATCH * K_IN)      x = (const float*)d_in[i];
            else if (in_sizes[i] == N_OUT * K_IN)   w = (const float*)d_in[i];
            else if (nsmall < 2) small[nsmall++] = (const float*)d_in[i];
        }
        if (nsmall == 2) { bias = small[0]; sign = small[1]; }
    }

    float* out = (float*)d_out;

    if (ws_size >= WS_NEED) {
        short* xhi = (short*)d_ws;
        short* xlo = xhi + XLO_SOFF;
        short* wtp = xhi + WT_SOFF;
        presplit19<<<2048, 512, 0, stream>>>(x, xhi, xlo);
        wconv19<<<128, 512, 0, stream>>>(w, wtp);
        // PROBE: staging-only (sink scribbles into out; K1 overwrites all)
        p_load19<<<1024, 256, 0, stream>>>(xhi, xlo, wtp, (int*)d_out);
        // K1: GEMM + decide (+ sentinel), no fixup
        binlin_g19<<<1024, 256, 0, stream>>>(xhi, xlo, wtp, bias, sign, out);
        // K2: scan + C3-exact fix of sentinels
        fixscan19<<<1024, 256, 0, stream>>>(x, w, bias, sign, out);
    } else {
        dim3 grid(N_OUT / 128, M_BATCH / 128);
        binlin_fast<<<grid, 256, 0, stream>>>(x, w, bias, sign, out);
    }
}

// Round 20
// 380.032 us; speedup vs baseline: 1.3906x; 1.1007x over previous
//
#include <hip/hip_runtime.h>
#include <hip/hip_bf16.h>

#define M_BATCH 65536
#define K_IN    1024
#define N_OUT   256
#define TAU     0.015f

// d_ws layout: xhi [65536][1024] bf16, xlo same, wt [256][1024] bf16,
// then counter (256B-aligned) + worklist (1M u32).
#define XLO_SOFF 67108864ULL
#define WT_SOFF  134217728ULL
#define CNT_BOFF 268959744ULL                 // byte offset of counter
#define WL_BOFF  (CNT_BOFF + 256ULL)          // byte offset of worklist
#define WL_CAP   1048576ULL                   // entries
#define WS_NEED  (WL_BOFF + WL_CAP * 4ULL)    // ~273 MB

typedef __attribute__((ext_vector_type(8))) short short8;
typedef __attribute__((ext_vector_type(4))) short short4v;
typedef __attribute__((ext_vector_type(4))) float f32x4;

__device__ inline short f2bf(float f) {
    __hip_bfloat16 h = __float2bfloat16(f);
    return __builtin_bit_cast(short, h);
}
__device__ inline float bf2f(short s) {
    unsigned u = ((unsigned)(unsigned short)s) << 16;
    return __builtin_bit_cast(float, u);
}
__device__ inline void gload16(const void* g, void* lds) {
    __builtin_amdgcn_global_load_lds(
        (const __attribute__((address_space(1))) unsigned int*)g,
        (__attribute__((address_space(3))) unsigned int*)lds, 16, 0, 0);
}

// C3-exact score (r8-verified reference ordering): kc=512 panels, ONE
// sequential f32 chain per panel, cs = p0 + p1; loads pipelined 1-ahead.
__device__ inline float c3_score(const float* __restrict__ xr_,
                                 const float* __restrict__ wr_) {
    float a0 = 0.f, a1 = 0.f;
    float4 xc0 = *(const float4*)(xr_);
    float4 wc0 = *(const float4*)(wr_);
    float4 xc1 = *(const float4*)(xr_ + 512);
    float4 wc1 = *(const float4*)(wr_ + 512);
    for (int k4 = 0; k4 < 128; ++k4) {
        const int kn = (k4 + 1) & 127;
        const float4 nx0 = *(const float4*)(xr_ + kn * 4);
        const float4 nw0 = *(const float4*)(wr_ + kn * 4);
        const float4 nx1 = *(const float4*)(xr_ + 512 + kn * 4);
        const float4 nw1 = *(const float4*)(wr_ + 512 + kn * 4);
        a0 = fmaf(xc0.x, wc0.x, a0); a1 = fmaf(xc1.x, wc1.x, a1);
        a0 = fmaf(xc0.y, wc0.y, a0); a1 = fmaf(xc1.y, wc1.y, a1);
        a0 = fmaf(xc0.z, wc0.z, a0); a1 = fmaf(xc1.z, wc1.z, a1);
        a0 = fmaf(xc0.w, wc0.w, a0); a1 = fmaf(xc1.w, wc1.w, a1);
        xc0 = nx0; wc0 = nw0; xc1 = nx1; wc1 = nw1;
    }
    return a0 + a1;
}

// Swizzled destination offset (shorts): within each 64-k block, 16B cell c
// stored at c ^ (row & 7) (rule #21; r16-r19 verified end-to-end).
__device__ inline size_t swz_dst(int row, int col4 /*float4 idx*/) {
    const int kb = col4 >> 4;
    const int c  = (col4 >> 1) & 7;
    const int h  = col4 & 1;
    return (size_t)row * K_IN + kb * 64 + ((c ^ (row & 7)) << 3) + h * 4;
}

// ---- x -> bf16 hi/lo, swizzled layout ----
__global__ __launch_bounds__(512) void presplit20(const float* __restrict__ x,
                                                  short* __restrict__ xhi,
                                                  short* __restrict__ xlo) {
    const int stride = gridDim.x * 512;
    for (int idx = blockIdx.x * 512 + threadIdx.x; idx < M_BATCH * (K_IN / 4); idx += stride) {
        const int row  = idx >> 8;
        const int col4 = idx & 255;
        const float4 v = ((const float4*)x)[idx];
        short4v h, l;
        h.x = f2bf(v.x); l.x = f2bf(v.x - bf2f(h.x));
        h.y = f2bf(v.y); l.y = f2bf(v.y - bf2f(h.y));
        h.z = f2bf(v.z); l.z = f2bf(v.z - bf2f(h.z));
        h.w = f2bf(v.w); l.w = f2bf(v.w - bf2f(h.w));
        const size_t dst = swz_dst(row, col4);
        *(short4v*)(xhi + dst) = h;
        *(short4v*)(xlo + dst) = l;
    }
}

// ---- W -> bf16 (exact: ternary), swizzled; also zeroes the worklist counter
__global__ __launch_bounds__(512) void wconv20(const float* __restrict__ w,
                                               short* __restrict__ wt,
                                               unsigned* __restrict__ counter) {
    if (blockIdx.x == 0 && threadIdx.x == 0) *counter = 0u;
    const int idx  = blockIdx.x * 512 + threadIdx.x;   // 65536 float4 total
    const int row  = idx >> 8;
    const int col4 = idx & 255;
    const float4 v = ((const float4*)w)[idx];
    short4v h;
    h.x = f2bf(v.x); h.y = f2bf(v.y); h.z = f2bf(v.z); h.w = f2bf(v.w);
    *(short4v*)(wt + swz_dst(row, col4)) = h;
}

// ---- K1: m97-structure MFMA GEMM (r19-verified, ~105us). Band cells append
// (m<<8|n) to the worklist (K2 fixes them); fast decision everywhere.
__global__ __launch_bounds__(256) void binlin_g20(const float* __restrict__ x,
                                                  const float* __restrict__ wf,
                                                  const short* __restrict__ xhi,
                                                  const short* __restrict__ xlo,
                                                  const short* __restrict__ wt,
                                                  const float* __restrict__ bias,
                                                  const float* __restrict__ sign,
                                                  float* __restrict__ out,
                                                  unsigned* __restrict__ counter,
                                                  unsigned* __restrict__ wl) {
    __shared__ __align__(16) short smem[24576];   // Ah 8K | Al 8K | B 8K shorts

    const int bid     = blockIdx.x;                 // 0..1023
    const int logical = (bid & 7) * 128 + (bid >> 3);
    const int m0 = (logical >> 1) * 128;
    const int n0 = (logical & 1) * 128;

    const int tid  = threadIdx.x;
    const int lane = tid & 63;
    const int wid  = tid >> 6;       // 4 waves: 2(m) x 2(n)
    const int wm   = wid >> 1;
    const int wn   = wid & 1;
    const int l15  = lane & 15;
    const int l4   = lane >> 4;

    const int srow = wid * 32 + (lane >> 3);
    const int scol = (lane & 7) * 8;
    const size_t asrc = (size_t)(m0 + srow) * K_IN + scol;
    const size_t bsrc = (size_t)(n0 + srow) * K_IN + scol;

    f32x4 acc[4][4];
#pragma unroll
    for (int i = 0; i < 4; ++i)
#pragma unroll
        for (int j = 0; j < 4; ++j) acc[i][j] = (f32x4){0.f, 0.f, 0.f, 0.f};

    short* Ah = smem;
    short* Al = smem + 8192;
    short* Bs = smem + 16384;

    for (int kt = 0; kt < 16; ++kt) {
        __syncthreads();
#pragma unroll
        for (int q = 0; q < 4; ++q) {
            gload16(xhi + asrc + (size_t)q * 8 * K_IN + kt * 64, Ah + (wid * 32 + q * 8) * 64);
            gload16(xlo + asrc + (size_t)q * 8 * K_IN + kt * 64, Al + (wid * 32 + q * 8) * 64);
            gload16(wt  + bsrc + (size_t)q * 8 * K_IN + kt * 64, Bs + (wid * 32 + q * 8) * 64);
        }
        __syncthreads();

#pragma unroll
        for (int kk = 0; kk < 2; ++kk) {
            short8 bfr[4];
#pragma unroll
            for (int ni = 0; ni < 4; ++ni) {
                const int Rn = wn * 64 + ni * 16 + l15;
                bfr[ni] = *(const short8*)&Bs[Rn * 64 + (((kk * 4 + l4) ^ (Rn & 7)) << 3)];
            }
#pragma unroll
            for (int mi = 0; mi < 4; ++mi) {
                const int Rm  = wm * 64 + mi * 16 + l15;
                const int off = Rm * 64 + (((kk * 4 + l4) ^ (Rm & 7)) << 3);
                const short8 ahi = *(const short8*)&Ah[off];
                const short8 alo = *(const short8*)&Al[off];
#pragma unroll
                for (int ni = 0; ni < 4; ++ni) {
                    acc[mi][ni] = __builtin_amdgcn_mfma_f32_16x16x32_bf16(
                        ahi, bfr[ni], acc[mi][ni], 0, 0, 0);
                    acc[mi][ni] = __builtin_amdgcn_mfma_f32_16x16x32_bf16(
                        alo, bfr[ni], acc[mi][ni], 0, 0, 0);
                }
            }
        }
    }
    __syncthreads();

    // epilogue: fast decision everywhere; band cells -> worklist
    unsigned char* dec = (unsigned char*)smem;      // 16 KB overlay [128][128]
#pragma unroll
    for (int ni = 0; ni < 4; ++ni) {
        const int nl = wn * 64 + ni * 16 + l15;
        const int n  = n0 + nl;
        const float b = bias[n];
        const float s = sign[n];
#pragma unroll
        for (int mi = 0; mi < 4; ++mi) {
            const int ml = wm * 64 + mi * 16 + l4 * 4;
#pragma unroll
            for (int j = 0; j < 4; ++j) {
                const float t = (acc[mi][ni][j] + b) * s;
                unsigned char d = (t >= -0.5f) ? 1 : 0;
                if (fabsf(t + 0.5f) < TAU) {
                    const int m = m0 + ml + j;
                    const unsigned idx = atomicAdd(counter, 1u);
                    if (idx < WL_CAP) {
                        wl[idx] = ((unsigned)m << 8) | (unsigned)n;
                    } else {
                        // overflow (never expected): exact inline
                        const float cs = c3_score(x + (size_t)m * K_IN,
                                                  wf + (size_t)n * K_IN);
                        d = (((cs + b) * s) >= -0.5f) ? 1 : 0;
                    }
                }
                dec[(ml + j) * 128 + nl] = d;
            }
        }
    }
    __syncthreads();

#pragma unroll
    for (int it = 0; it < 16; ++it) {
        const int f   = it * 256 + tid;   // float4 index in 128x128 tile
        const int row = f >> 5;
        const int c4  = f & 31;
        const uchar4 dv = *(const uchar4*)&dec[row * 128 + c4 * 4];
        *(float4*)(out + (size_t)(m0 + row) * N_OUT + n0 + c4 * 4) =
            make_float4((float)dv.x, (float)dv.y, (float)dv.z, (float)dv.w);
    }
}

// ---- K2: fix worklist cells with the C3-exact chain (one thread per item)
__global__ __launch_bounds__(256) void fixwl20(const float* __restrict__ x,
                                               const float* __restrict__ wf,
                                               const float* __restrict__ bias,
                                               const float* __restrict__ sign,
                                               const unsigned* __restrict__ counter,
                                               const unsigned* __restrict__ wl,
                                               float* __restrict__ out) {
    const unsigned count = min(*counter, (unsigned)WL_CAP);
    const unsigned stride = gridDim.x * 256;
    for (unsigned i = blockIdx.x * 256 + threadIdx.x; i < count; i += stride) {
        const unsigned code = wl[i];
        const int m = (int)(code >> 8);
        const int n = (int)(code & 255u);
        const float cs = c3_score(x + (size_t)m * K_IN, wf + (size_t)n * K_IN);
        const float tt = (cs + bias[n]) * sign[n];
        out[(size_t)m * N_OUT + n] = (tt >= -0.5f) ? 1.0f : 0.0f;
    }
}

// ---- fallback (r9-proven): fp32 tiled GEMM + inline C3 band fixup ----
__global__ __launch_bounds__(256) void binlin_fast(const float* __restrict__ x,
                                                   const float* __restrict__ w,
                                                   const float* __restrict__ bias,
                                                   const float* __restrict__ sign,
                                                   float* __restrict__ out) {
    __shared__ float As[32][132];
    __shared__ float Bs2[32][132];
    const int tid = threadIdx.x;
    const int tx  = tid & 15;
    const int ty  = tid >> 4;
    const int n0  = blockIdx.x * 128;
    const int m0  = blockIdx.y * 128;
    const int sr  = tid >> 3;
    const int sc  = (tid & 7) * 4;
    float acc[8][8];
#pragma unroll
    for (int i = 0; i < 8; ++i)
#pragma unroll
        for (int j = 0; j < 8; ++j) acc[i][j] = 0.f;
    for (int kt = 0; kt < K_IN; kt += 32) {
        __syncthreads();
#pragma unroll
        for (int q = 0; q < 4; ++q) {
            const int row = sr + q * 32;
            const float4 va = *(const float4*)(x + (size_t)(m0 + row) * K_IN + kt + sc);
            As[sc + 0][row] = va.x; As[sc + 1][row] = va.y;
            As[sc + 2][row] = va.z; As[sc + 3][row] = va.w;
            const float4 vb = *(const float4*)(w + (size_t)(n0 + row) * K_IN + kt + sc);
            Bs2[sc + 0][row] = vb.x; Bs2[sc + 1][row] = vb.y;
            Bs2[sc + 2][row] = vb.z; Bs2[sc + 3][row] = vb.w;
        }
        __syncthreads();
#pragma unroll
        for (int kk = 0; kk < 32; ++kk) {
            const float4 a0 = *(const float4*)&As[kk][ty * 8];
            const float4 a1 = *(const float4*)&As[kk][ty * 8 + 4];
            const float4 b0 = *(const float4*)&Bs2[kk][tx * 8];
            const float4 b1 = *(const float4*)&Bs2[kk][tx * 8 + 4];
            const float a[8] = {a0.x, a0.y, a0.z, a0.w, a1.x, a1.y, a1.z, a1.w};
            const float b[8] = {b0.x, b0.y, b0.z, b0.w, b1.x, b1.y, b1.z, b1.w};
#pragma unroll
            for (int i = 0; i < 8; ++i)
#pragma unroll
                for (int j = 0; j < 8; ++j)
                    acc[i][j] = fmaf(a[i], b[j], acc[i][j]);
        }
    }
    const int nb = n0 + tx * 8;
    float bv[8], sv[8];
#pragma unroll
    for (int j = 0; j < 8; ++j) { bv[j] = bias[nb + j]; sv[j] = sign[nb + j]; }
#pragma unroll
    for (int i = 0; i < 8; ++i) {
        const int m = m0 + ty * 8 + i;
        float o[8];
#pragma unroll
        for (int j = 0; j < 8; ++j) {
            const float t = (acc[i][j] + bv[j]) * sv[j];
            if (fabsf(t + 0.5f) < TAU) {
                const float cs = c3_score(x + (size_t)m * K_IN,
                                          w + (size_t)(nb + j) * K_IN);
                o[j] = (((cs + bv[j]) * sv[j]) >= -0.5f) ? 1.0f : 0.0f;
            } else {
                o[j] = (t >= -0.5f) ? 1.0f : 0.0f;
            }
        }
        float4* op = (float4*)(out + (size_t)m * N_OUT + nb);
        op[0] = make_float4(o[0], o[1], o[2], o[3]);
        op[1] = make_float4(o[4], o[5], o[6], o[7]);
    }
}

extern "C" void kernel_launch(void* const* d_in, const int* in_sizes, int n_in,
                              void* d_out, int out_size, void* d_ws, size_t ws_size,
                              hipStream_t stream) {
    const float* x    = (const float*)d_in[0];
    const float* w    = (const float*)d_in[1];
    const float* bias = (const float*)d_in[2];
    const float* sign = (const float*)d_in[3];

    if (n_in >= 4 && in_sizes[0] != M_BATCH * K_IN) {   // defensive no-op
        const float* small[2] = {nullptr, nullptr};
        int nsmall = 0;
        for (int i = 0; i < 4; ++i) {
            if (in_sizes[i] == M_BATCH * K_IN)      x = (const float*)d_in[i];
            else if (in_sizes[i] == N_OUT * K_IN)   w = (const float*)d_in[i];
            else if (nsmall < 2) small[nsmall++] = (const float*)d_in[i];
        }
        if (nsmall == 2) { bias = small[0]; sign = small[1]; }
    }

    float* out = (float*)d_out;

    if (ws_size >= WS_NEED) {
        short*    xhi = (short*)d_ws;
        short*    xlo = xhi + XLO_SOFF;
        short*    wtp = xhi + WT_SOFF;
        unsigned* cnt = (unsigned*)((char*)d_ws + CNT_BOFF);
        unsigned* wl  = (unsigned*)((char*)d_ws + WL_BOFF);

        presplit20<<<2048, 512, 0, stream>>>(x, xhi, xlo);
        wconv20<<<128, 512, 0, stream>>>(w, wtp, cnt);
        binlin_g20<<<1024, 256, 0, stream>>>(x, w, xhi, xlo, wtp, bias, sign,
                                             out, cnt, wl);
        fixwl20<<<256, 256, 0, stream>>>(x, w, bias, sign, cnt, wl, out);
    } else {
        dim3 grid(N_OUT / 128, M_BATCH / 128);
        binlin_fast<<<grid, 256, 0, stream>>>(x, w, bias, sign, out);
    }
}

// Round 21
// 311.222 us; speedup vs baseline: 1.6980x; 1.2211x over previous
//
#include <hip/hip_runtime.h>
#include <hip/hip_bf16.h>

#define M_BATCH 65536
#define K_IN    1024
#define N_OUT   256
#define TAU     0.015f

// d_ws layout: wt [256][1024] bf16 (512KB), counter, worklist (1M u32)
#define CNT_BOFF 524288ULL
#define WL_BOFF  524544ULL
#define WL_CAP   1048576ULL
#define WS_NEED  (WL_BOFF + WL_CAP * 4ULL)   // ~4.7 MB

typedef __attribute__((ext_vector_type(8))) short short8;
typedef __attribute__((ext_vector_type(4))) short short4v;
typedef __attribute__((ext_vector_type(4))) float f32x4;

__device__ inline short f2bf(float f) {
    __hip_bfloat16 h = __float2bfloat16(f);
    return __builtin_bit_cast(short, h);
}
__device__ inline float bf2f(short s) {
    unsigned u = ((unsigned)(unsigned short)s) << 16;
    return __builtin_bit_cast(float, u);
}

// C3-exact score (r8-verified reference ordering): kc=512 panels, ONE
// sequential f32 chain per panel, cs = p0 + p1; loads pipelined 1-ahead.
__device__ inline float c3_score(const float* __restrict__ xr_,
                                 const float* __restrict__ wr_) {
    float a0 = 0.f, a1 = 0.f;
    float4 xc0 = *(const float4*)(xr_);
    float4 wc0 = *(const float4*)(wr_);
    float4 xc1 = *(const float4*)(xr_ + 512);
    float4 wc1 = *(const float4*)(wr_ + 512);
    for (int k4 = 0; k4 < 128; ++k4) {
        const int kn = (k4 + 1) & 127;
        const float4 nx0 = *(const float4*)(xr_ + kn * 4);
        const float4 nw0 = *(const float4*)(wr_ + kn * 4);
        const float4 nx1 = *(const float4*)(xr_ + 512 + kn * 4);
        const float4 nw1 = *(const float4*)(wr_ + 512 + kn * 4);
        a0 = fmaf(xc0.x, wc0.x, a0); a1 = fmaf(xc1.x, wc1.x, a1);
        a0 = fmaf(xc0.y, wc0.y, a0); a1 = fmaf(xc1.y, wc1.y, a1);
        a0 = fmaf(xc0.z, wc0.z, a0); a1 = fmaf(xc1.z, wc1.z, a1);
        a0 = fmaf(xc0.w, wc0.w, a0); a1 = fmaf(xc1.w, wc1.w, a1);
        xc0 = nx0; wc0 = nw0; xc1 = nx1; wc1 = nw1;
    }
    return a0 + a1;
}

// ---- W -> bf16 (exact: ternary), LINEAR layout; zeroes worklist counter ----
__global__ __launch_bounds__(512) void wconv21(const float* __restrict__ w,
                                               short* __restrict__ wt,
                                               unsigned* __restrict__ counter) {
    if (blockIdx.x == 0 && threadIdx.x == 0) *counter = 0u;
    const int idx = blockIdx.x * 512 + threadIdx.x;   // 65536 float4 total
    const float4 v = ((const float4*)w)[idx];
    short4v h;
    h.x = f2bf(v.x); h.y = f2bf(v.y); h.z = f2bf(v.z); h.w = f2bf(v.w);
    ((short4v*)wt)[idx] = h;
}

// ---- fused main: barrier-free MFMA GEMM reading x (f32) DIRECTLY.
// 128x128 tile, 4 waves (2m x 2n). A: f32 global->reg (16-line coalesced,
// r18-verified pattern), hi/lo split in registers (static unroll, rule #20),
// fed straight to MFMA - A never touches LDS, presplit kernel eliminated.
// B: short8 fragments direct from linear wt (512KB, L2-resident).
// NO main-loop barriers: wave-level MFMA/VALU/VMEM overlap (m114) hides
// latency across ~12 waves/CU. XCD-pair swizzle: each m-panel's two
// n-blocks co-reside on one XCD -> x HBM-fetched once, 2nd read L2-hit.
// Band cells |t+0.5| < TAU -> worklist (r20-proven); fixwl runs C3-exact.
__global__ __launch_bounds__(256) void binlin_f21(const float* __restrict__ x,
                                                  const float* __restrict__ wf,
                                                  const short* __restrict__ wt,
                                                  const float* __restrict__ bias,
                                                  const float* __restrict__ sign,
                                                  float* __restrict__ out,
                                                  unsigned* __restrict__ counter,
                                                  unsigned* __restrict__ wl) {
    __shared__ __align__(16) unsigned char dec[16384];   // epilogue only

    const int bid     = blockIdx.x;                 // 0..1023
    const int logical = (bid & 7) * 128 + (bid >> 3);
    const int m0 = (logical >> 1) * 128;
    const int n0 = (logical & 1) * 128;

    const int tid  = threadIdx.x;
    const int lane = tid & 63;
    const int wid  = tid >> 6;       // 4 waves: 2(m) x 2(n)
    const int wm   = wid >> 1;
    const int wn   = wid & 1;
    const int l15  = lane & 15;
    const int l4   = lane >> 4;

    const float* abase = x  + (size_t)(m0 + wm * 64 + l15) * K_IN + l4 * 8;
    const short* bbase = wt + (size_t)(n0 + wn * 64 + l15) * K_IN + l4 * 8;

    f32x4 acc[4][4];
#pragma unroll
    for (int i = 0; i < 4; ++i)
#pragma unroll
        for (int j = 0; j < 4; ++j) acc[i][j] = (f32x4){0.f, 0.f, 0.f, 0.f};

    for (int kt = 0; kt < 16; ++kt) {
#pragma unroll
        for (int kk = 0; kk < 2; ++kk) {
            const int ko = kt * 64 + kk * 32;
            short8 bfr[4];
#pragma unroll
            for (int ni = 0; ni < 4; ++ni)
                bfr[ni] = *(const short8*)(bbase + (size_t)ni * 16 * K_IN + ko);
#pragma unroll
            for (int mi = 0; mi < 4; ++mi) {
                const float4 f0 = *(const float4*)(abase + (size_t)mi * 16 * K_IN + ko);
                const float4 f1 = *(const float4*)(abase + (size_t)mi * 16 * K_IN + ko + 4);
                const float fv[8] = {f0.x, f0.y, f0.z, f0.w, f1.x, f1.y, f1.z, f1.w};
                short8 ahi, alo;
#pragma unroll
                for (int e = 0; e < 8; ++e) {
                    const short h = f2bf(fv[e]);
                    ahi[e] = h;
                    alo[e] = f2bf(fv[e] - bf2f(h));
                }
#pragma unroll
                for (int ni = 0; ni < 4; ++ni) {
                    acc[mi][ni] = __builtin_amdgcn_mfma_f32_16x16x32_bf16(
                        ahi, bfr[ni], acc[mi][ni], 0, 0, 0);
                    acc[mi][ni] = __builtin_amdgcn_mfma_f32_16x16x32_bf16(
                        alo, bfr[ni], acc[mi][ni], 0, 0, 0);
                }
            }
        }
    }

    // ---- epilogue: fast decision; band -> worklist; u8 LDS -> float4 out
#pragma unroll
    for (int ni = 0; ni < 4; ++ni) {
        const int nl = wn * 64 + ni * 16 + l15;
        const int n  = n0 + nl;
        const float b = bias[n];
        const float s = sign[n];
#pragma unroll
        for (int mi = 0; mi < 4; ++mi) {
            const int ml = wm * 64 + mi * 16 + l4 * 4;
#pragma unroll
            for (int j = 0; j < 4; ++j) {
                const float t = (acc[mi][ni][j] + b) * s;
                unsigned char d = (t >= -0.5f) ? 1 : 0;
                if (fabsf(t + 0.5f) < TAU) {
                    const int m = m0 + ml + j;
                    const unsigned idx = atomicAdd(counter, 1u);
                    if (idx < WL_CAP) {
                        wl[idx] = ((unsigned)m << 8) | (unsigned)n;
                    } else {
                        const float cs = c3_score(x + (size_t)m * K_IN,
                                                  wf + (size_t)n * K_IN);
                        d = (((cs + b) * s) >= -0.5f) ? 1 : 0;
                    }
                }
                dec[(ml + j) * 128 + nl] = d;
            }
        }
    }
    __syncthreads();

#pragma unroll
    for (int it = 0; it < 16; ++it) {
        const int f   = it * 256 + tid;   // float4 index in 128x128 tile
        const int row = f >> 5;
        const int c4  = f & 31;
        const uchar4 dv = *(const uchar4*)&dec[row * 128 + c4 * 4];
        *(float4*)(out + (size_t)(m0 + row) * N_OUT + n0 + c4 * 4) =
            make_float4((float)dv.x, (float)dv.y, (float)dv.z, (float)dv.w);
    }
}

// ---- K2: fix worklist cells with the C3-exact chain (one thread per item)
__global__ __launch_bounds__(256) void fixwl21(const float* __restrict__ x,
                                               const float* __restrict__ wf,
                                               const float* __restrict__ bias,
                                               const float* __restrict__ sign,
                                               const unsigned* __restrict__ counter,
                                               const unsigned* __restrict__ wl,
                                               float* __restrict__ out) {
    const unsigned count = min(*counter, (unsigned)WL_CAP);
    const unsigned stride = gridDim.x * 256;
    for (unsigned i = blockIdx.x * 256 + threadIdx.x; i < count; i += stride) {
        const unsigned code = wl[i];
        const int m = (int)(code >> 8);
        const int n = (int)(code & 255u);
        const float cs = c3_score(x + (size_t)m * K_IN, wf + (size_t)n * K_IN);
        const float tt = (cs + bias[n]) * sign[n];
        out[(size_t)m * N_OUT + n] = (tt >= -0.5f) ? 1.0f : 0.0f;
    }
}

// ---- fallback (r9-proven): fp32 tiled GEMM + inline C3 band fixup ----
__global__ __launch_bounds__(256) void binlin_fast(const float* __restrict__ x,
                                                   const float* __restrict__ w,
                                                   const float* __restrict__ bias,
                                                   const float* __restrict__ sign,
                                                   float* __restrict__ out) {
    __shared__ float As[32][132];
    __shared__ float Bs2[32][132];
    const int tid = threadIdx.x;
    const int tx  = tid & 15;
    const int ty  = tid >> 4;
    const int n0  = blockIdx.x * 128;
    const int m0  = blockIdx.y * 128;
    const int sr  = tid >> 3;
    const int sc  = (tid & 7) * 4;
    float acc[8][8];
#pragma unroll
    for (int i = 0; i < 8; ++i)
#pragma unroll
        for (int j = 0; j < 8; ++j) acc[i][j] = 0.f;
    for (int kt = 0; kt < K_IN; kt += 32) {
        __syncthreads();
#pragma unroll
        for (int q = 0; q < 4; ++q) {
            const int row = sr + q * 32;
            const float4 va = *(const float4*)(x + (size_t)(m0 + row) * K_IN + kt + sc);
            As[sc + 0][row] = va.x; As[sc + 1][row] = va.y;
            As[sc + 2][row] = va.z; As[sc + 3][row] = va.w;
            const float4 vb = *(const float4*)(w + (size_t)(n0 + row) * K_IN + kt + sc);
            Bs2[sc + 0][row] = vb.x; Bs2[sc + 1][row] = vb.y;
            Bs2[sc + 2][row] = vb.z; Bs2[sc + 3][row] = vb.w;
        }
        __syncthreads();
#pragma unroll
        for (int kk = 0; kk < 32; ++kk) {
            const float4 a0 = *(const float4*)&As[kk][ty * 8];
            const float4 a1 = *(const float4*)&As[kk][ty * 8 + 4];
            const float4 b0 = *(const float4*)&Bs2[kk][tx * 8];
            const float4 b1 = *(const float4*)&Bs2[kk][tx * 8 + 4];
            const float a[8] = {a0.x, a0.y, a0.z, a0.w, a1.x, a1.y, a1.z, a1.w};
            const float b[8] = {b0.x, b0.y, b0.z, b0.w, b1.x, b1.y, b1.z, b1.w};
#pragma unroll
            for (int i = 0; i < 8; ++i)
#pragma unroll
                for (int j = 0; j < 8; ++j)
                    acc[i][j] = fmaf(a[i], b[j], acc[i][j]);
        }
    }
    const int nb = n0 + tx * 8;
    float bv[8], sv[8];
#pragma unroll
    for (int j = 0; j < 8; ++j) { bv[j] = bias[nb + j]; sv[j] = sign[nb + j]; }
#pragma unroll
    for (int i = 0; i < 8; ++i) {
        const int m = m0 + ty * 8 + i;
        float o[8];
#pragma unroll
        for (int j = 0; j < 8; ++j) {
            const float t = (acc[i][j] + bv[j]) * sv[j];
            if (fabsf(t + 0.5f) < TAU) {
                const float cs = c3_score(x + (size_t)m * K_IN,
                                          w + (size_t)(nb + j) * K_IN);
                o[j] = (((cs + bv[j]) * sv[j]) >= -0.5f) ? 1.0f : 0.0f;
            } else {
                o[j] = (t >= -0.5f) ? 1.0f : 0.0f;
            }
        }
        float4* op = (float4*)(out + (size_t)m * N_OUT + nb);
        op[0] = make_float4(o[0], o[1], o[2], o[3]);
        op[1] = make_float4(o[4], o[5], o[6], o[7]);
    }
}

extern "C" void kernel_launch(void* const* d_in, const int* in_sizes, int n_in,
                              void* d_out, int out_size, void* d_ws, size_t ws_size,
                              hipStream_t stream) {
    const float* x    = (const float*)d_in[0];
    const float* w    = (const float*)d_in[1];
    const float* bias = (const float*)d_in[2];
    const float* sign = (const float*)d_in[3];

    if (n_in >= 4 && in_sizes[0] != M_BATCH * K_IN) {   // defensive no-op
        const float* small[2] = {nullptr, nullptr};
        int nsmall = 0;
        for (int i = 0; i < 4; ++i) {
            if (in_sizes[i] == M_BATCH * K_IN)      x = (const float*)d_in[i];
            else if (in_sizes[i] == N_OUT * K_IN)   w = (const float*)d_in[i];
            else if (nsmall < 2) small[nsmall++] = (const float*)d_in[i];
        }
        if (nsmall == 2) { bias = small[0]; sign = small[1]; }
    }

    float* out = (float*)d_out;

    if (ws_size >= WS_NEED) {
        short*    wtp = (short*)d_ws;
        unsigned* cnt = (unsigned*)((char*)d_ws + CNT_BOFF);
        unsigned* wl  = (unsigned*)((char*)d_ws + WL_BOFF);

        wconv21<<<128, 512, 0, stream>>>(w, wtp, cnt);
        binlin_f21<<<1024, 256, 0, stream>>>(x, w, wtp, bias, sign, out, cnt, wl);
        fixwl21<<<256, 256, 0, stream>>>(x, w, bias, sign, cnt, wl, out);
    } else {
        dim3 grid(N_OUT / 128, M_BATCH / 128);
        binlin_fast<<<grid, 256, 0, stream>>>(x, w, bias, sign, out);
    }
}

// Round 22
// 307.335 us; speedup vs baseline: 1.7195x; 1.0126x over previous
//
#include <hip/hip_runtime.h>
#include <hip/hip_bf16.h>

#define M_BATCH 65536
#define K_IN    1024
#define N_OUT   256
#define TAU     0.015f

// d_ws layout: wt [256][1024] bf16 (512KB), counter, worklist (1M u32)
#define CNT_BOFF 524288ULL
#define WL_BOFF  524544ULL
#define WL_CAP   1048576ULL
#define WS_NEED  (WL_BOFF + WL_CAP * 4ULL)   // ~4.7 MB

// LDS byte offsets: A0/A1 = 16KB f32 x-tiles, B0/B1 = 8KB bf16 w-tiles
#define A0_OFF 0
#define A1_OFF 16384
#define B0_OFF 32768
#define B1_OFF 40960

typedef __attribute__((ext_vector_type(8))) short short8;
typedef __attribute__((ext_vector_type(4))) short short4v;
typedef __attribute__((ext_vector_type(4))) float f32x4;

__device__ inline short f2bf(float f) {
    __hip_bfloat16 h = __float2bfloat16(f);
    return __builtin_bit_cast(short, h);
}
__device__ inline float bf2f(short s) {
    unsigned u = ((unsigned)(unsigned short)s) << 16;
    return __builtin_bit_cast(float, u);
}
__device__ inline void gload16(const void* g, void* lds) {
    __builtin_amdgcn_global_load_lds(
        (const __attribute__((address_space(1))) unsigned int*)g,
        (__attribute__((address_space(3))) unsigned int*)lds, 16, 0, 0);
}

// C3-exact score (r8-verified reference ordering): kc=512 panels, ONE
// sequential f32 chain per panel, cs = p0 + p1; loads pipelined 1-ahead.
__device__ inline float c3_score(const float* __restrict__ xr_,
                                 const float* __restrict__ wr_) {
    float a0 = 0.f, a1 = 0.f;
    float4 xc0 = *(const float4*)(xr_);
    float4 wc0 = *(const float4*)(wr_);
    float4 xc1 = *(const float4*)(xr_ + 512);
    float4 wc1 = *(const float4*)(wr_ + 512);
    for (int k4 = 0; k4 < 128; ++k4) {
        const int kn = (k4 + 1) & 127;
        const float4 nx0 = *(const float4*)(xr_ + kn * 4);
        const float4 nw0 = *(const float4*)(wr_ + kn * 4);
        const float4 nx1 = *(const float4*)(xr_ + 512 + kn * 4);
        const float4 nw1 = *(const float4*)(wr_ + 512 + kn * 4);
        a0 = fmaf(xc0.x, wc0.x, a0); a1 = fmaf(xc1.x, wc1.x, a1);
        a0 = fmaf(xc0.y, wc0.y, a0); a1 = fmaf(xc1.y, wc1.y, a1);
        a0 = fmaf(xc0.z, wc0.z, a0); a1 = fmaf(xc1.z, wc1.z, a1);
        a0 = fmaf(xc0.w, wc0.w, a0); a1 = fmaf(xc1.w, wc1.w, a1);
        xc0 = nx0; wc0 = nw0; xc1 = nx1; wc1 = nw1;
    }
    return a0 + a1;
}

// ---- W -> bf16 (exact: ternary), LINEAR; zeroes worklist counter ----
__global__ __launch_bounds__(512) void wconv22(const float* __restrict__ w,
                                               short* __restrict__ wt,
                                               unsigned* __restrict__ counter) {
    if (blockIdx.x == 0 && threadIdx.x == 0) *counter = 0u;
    const int idx = blockIdx.x * 512 + threadIdx.x;   // 65536 float4 total
    const float4 v = ((const float4*)w)[idx];
    short4v h;
    h.x = f2bf(v.x); h.y = f2bf(v.y); h.z = f2bf(v.z); h.w = f2bf(v.w);
    ((short4v*)wt)[idx] = h;
}

// ---- fused main: 2-phase double-buffered gload_lds GEMM, x staged as f32
// (no presplit), hi/lo split in registers after the LDS read. Swizzle lives
// in the per-lane global SOURCE address (rule #21, kt-invariant):
//   A (f32, [128][32]): cell(16B) c stored at c ^ ((row&3)<<1)  (bit0 kept ->
//       fragment pair stays adjacent; 4-way read conflict, 1.58x)
//   B (bf16, [128][32]): cell c stored at c ^ (row&3)  (2-way = free)
// Schedule/step: STAGE(next buf) issued BEFORE compute(cur); 1 barrier/step
// (T3 minimum 2-phase; stage latency overlaps ds_read+convert+MFMA).
// Band cells -> worklist (r20/r21-proven); fixwl runs the C3-exact chain.
__global__ __launch_bounds__(256) void binlin_db22(const float* __restrict__ x,
                                                   const float* __restrict__ wf,
                                                   const short* __restrict__ wt,
                                                   const float* __restrict__ bias,
                                                   const float* __restrict__ sign,
                                                   float* __restrict__ out,
                                                   unsigned* __restrict__ counter,
                                                   unsigned* __restrict__ wl) {
    __shared__ __align__(16) unsigned char smem[49152];

    const int bid     = blockIdx.x;                 // 0..1023
    const int logical = (bid & 7) * 128 + (bid >> 3);
    const int m0 = (logical >> 1) * 128;
    const int n0 = (logical & 1) * 128;

    const int tid  = threadIdx.x;
    const int lane = tid & 63;
    const int wid  = tid >> 6;       // 4 waves: 2(m) x 2(n)
    const int wm   = wid >> 1;
    const int wn   = wid & 1;
    const int l15  = lane & 15;
    const int l4   = lane >> 4;

    // ---- staging source bases (per-lane, pre-swizzled, kt-invariant) ----
    // A: 4 insts/wave, inst q covers rows wid*32+q*8 .. +8 (8 rows x 8 cells)
    size_t xs0, xs1, xs2, xs3;
    {
        const int r  = lane >> 3;                   // 0..7 within inst
        const int cp = (lane & 7) ^ ((r & 3) << 1); // bit0-preserving XOR
#define XSRC(q) ((size_t)(m0 + wid * 32 + (q) * 8 + r) * K_IN + cp * 4)
        xs0 = XSRC(0); xs1 = XSRC(1); xs2 = XSRC(2); xs3 = XSRC(3);
#undef XSRC
    }
    // B: 2 insts/wave, inst q covers rows wid*32+q*16 .. +16 (16 rows x 4 cells)
    size_t bs0, bs1;
    {
        const int r  = lane >> 2;                   // 0..15 within inst
        const int cp = (lane & 3) ^ (r & 3);
        bs0 = (size_t)(n0 + wid * 32 + 0 * 16 + r) * K_IN + cp * 8;
        bs1 = (size_t)(n0 + wid * 32 + 1 * 16 + r) * K_IN + cp * 8;
    }
    // LDS wave-uniform dests (HW adds lane*16)
    const int xd0 = (wid * 32 + 0) * 128, xd1 = (wid * 32 + 8) * 128;
    const int xd2 = (wid * 32 + 16) * 128, xd3 = (wid * 32 + 24) * 128;
    const int bd0 = (wid * 32 + 0) * 64,  bd1 = (wid * 32 + 16) * 64;

#define STAGE(AOFF, BOFF, KT) {                                         \
        gload16(x + xs0 + (KT) * 32, smem + (AOFF) + xd0);              \
        gload16(x + xs1 + (KT) * 32, smem + (AOFF) + xd1);              \
        gload16(x + xs2 + (KT) * 32, smem + (AOFF) + xd2);              \
        gload16(x + xs3 + (KT) * 32, smem + (AOFF) + xd3);              \
        gload16(wt + bs0 + (KT) * 32, smem + (BOFF) + bd0);             \
        gload16(wt + bs1 + (KT) * 32, smem + (BOFF) + bd1);             }

    f32x4 acc[4][4];
#pragma unroll
    for (int i = 0; i < 4; ++i)
#pragma unroll
        for (int j = 0; j < 4; ++j) acc[i][j] = (f32x4){0.f, 0.f, 0.f, 0.f};

#define COMPUTE(AOFF, BOFF) {                                           \
        short8 bfr[4];                                                  \
        _Pragma("unroll")                                               \
        for (int ni = 0; ni < 4; ++ni) {                                \
            const int Rn = wn * 64 + ni * 16 + l15;                     \
            bfr[ni] = *(const short8*)(smem + (BOFF) + Rn * 64 +        \
                                       ((l4 ^ (Rn & 3)) << 4));         \
        }                                                               \
        _Pragma("unroll")                                               \
        for (int mi = 0; mi < 4; ++mi) {                                \
            const int Rm  = wm * 64 + mi * 16 + l15;                    \
            const int cp0 = (l4 * 2) ^ ((Rm & 3) << 1);                 \
            const float4 f0 = *(const float4*)(smem + (AOFF) + Rm * 128 + cp0 * 16); \
            const float4 f1 = *(const float4*)(smem + (AOFF) + Rm * 128 + cp0 * 16 + 16); \
            const float fv[8] = {f0.x, f0.y, f0.z, f0.w, f1.x, f1.y, f1.z, f1.w}; \
            short8 ahi, alo;                                            \
            _Pragma("unroll")                                           \
            for (int e = 0; e < 8; ++e) {                               \
                const short h = f2bf(fv[e]);                            \
                ahi[e] = h;                                             \
                alo[e] = f2bf(fv[e] - bf2f(h));                         \
            }                                                           \
            _Pragma("unroll")                                           \
            for (int ni = 0; ni < 4; ++ni) {                            \
                acc[mi][ni] = __builtin_amdgcn_mfma_f32_16x16x32_bf16(  \
                    ahi, bfr[ni], acc[mi][ni], 0, 0, 0);                \
                acc[mi][ni] = __builtin_amdgcn_mfma_f32_16x16x32_bf16(  \
                    alo, bfr[ni], acc[mi][ni], 0, 0, 0);                \
            }                                                           \
        }                                                               }

    STAGE(A0_OFF, B0_OFF, 0)
    __syncthreads();                  // vmcnt(0) drain: tile0 ready

    for (int it = 0; it < 16; ++it) {
        const int kt = it * 2;
        if (kt + 1 < 32) STAGE(A1_OFF, B1_OFF, kt + 1)   // overlap w/ compute
        COMPUTE(A0_OFF, B0_OFF)
        __syncthreads();              // tile kt+1 ready, buf0 free
        if (kt + 2 < 32) STAGE(A0_OFF, B0_OFF, kt + 2)
        COMPUTE(A1_OFF, B1_OFF)
        __syncthreads();              // tile kt+2 ready, buf1 free
    }

    // ---- epilogue: fast decision; band -> worklist; u8 LDS -> float4 out
    unsigned char* dec = smem;        // 16 KB overlay (post-loop, barrier'd)
#pragma unroll
    for (int ni = 0; ni < 4; ++ni) {
        const int nl = wn * 64 + ni * 16 + l15;
        const int n  = n0 + nl;
        const float b = bias[n];
        const float s = sign[n];
#pragma unroll
        for (int mi = 0; mi < 4; ++mi) {
            const int ml = wm * 64 + mi * 16 + l4 * 4;
#pragma unroll
            for (int j = 0; j < 4; ++j) {
                const float t = (acc[mi][ni][j] + b) * s;
                unsigned char d = (t >= -0.5f) ? 1 : 0;
                if (fabsf(t + 0.5f) < TAU) {
                    const int m = m0 + ml + j;
                    const unsigned idx = atomicAdd(counter, 1u);
                    if (idx < WL_CAP) {
                        wl[idx] = ((unsigned)m << 8) | (unsigned)n;
                    } else {
                        const float cs = c3_score(x + (size_t)m * K_IN,
                                                  wf + (size_t)n * K_IN);
                        d = (((cs + b) * s) >= -0.5f) ? 1 : 0;
                    }
                }
                dec[(ml + j) * 128 + nl] = d;
            }
        }
    }
    __syncthreads();

#pragma unroll
    for (int it = 0; it < 16; ++it) {
        const int f   = it * 256 + tid;   // float4 index in 128x128 tile
        const int row = f >> 5;
        const int c4  = f & 31;
        const uchar4 dv = *(const uchar4*)&dec[row * 128 + c4 * 4];
        *(float4*)(out + (size_t)(m0 + row) * N_OUT + n0 + c4 * 4) =
            make_float4((float)dv.x, (float)dv.y, (float)dv.z, (float)dv.w);
    }
}

// ---- K2: fix worklist cells with the C3-exact chain (one thread per item)
__global__ __launch_bounds__(256) void fixwl22(const float* __restrict__ x,
                                               const float* __restrict__ wf,
                                               const float* __restrict__ bias,
                                               const float* __restrict__ sign,
                                               const unsigned* __restrict__ counter,
                                               const unsigned* __restrict__ wl,
                                               float* __restrict__ out) {
    const unsigned count = min(*counter, (unsigned)WL_CAP);
    const unsigned stride = gridDim.x * 256;
    for (unsigned i = blockIdx.x * 256 + threadIdx.x; i < count; i += stride) {
        const unsigned code = wl[i];
        const int m = (int)(code >> 8);
        const int n = (int)(code & 255u);
        const float cs = c3_score(x + (size_t)m * K_IN, wf + (size_t)n * K_IN);
        const float tt = (cs + bias[n]) * sign[n];
        out[(size_t)m * N_OUT + n] = (tt >= -0.5f) ? 1.0f : 0.0f;
    }
}

// ---- fallback (r9-proven): fp32 tiled GEMM + inline C3 band fixup ----
__global__ __launch_bounds__(256) void binlin_fast(const float* __restrict__ x,
                                                   const float* __restrict__ w,
                                                   const float* __restrict__ bias,
                                                   const float* __restrict__ sign,
                                                   float* __restrict__ out) {
    __shared__ float As[32][132];
    __shared__ float Bs2[32][132];
    const int tid = threadIdx.x;
    const int tx  = tid & 15;
    const int ty  = tid >> 4;
    const int n0  = blockIdx.x * 128;
    const int m0  = blockIdx.y * 128;
    const int sr  = tid >> 3;
    const int sc  = (tid & 7) * 4;
    float acc[8][8];
#pragma unroll
    for (int i = 0; i < 8; ++i)
#pragma unroll
        for (int j = 0; j < 8; ++j) acc[i][j] = 0.f;
    for (int kt = 0; kt < K_IN; kt += 32) {
        __syncthreads();
#pragma unroll
        for (int q = 0; q < 4; ++q) {
            const int row = sr + q * 32;
            const float4 va = *(const float4*)(x + (size_t)(m0 + row) * K_IN + kt + sc);
            As[sc + 0][row] = va.x; As[sc + 1][row] = va.y;
            As[sc + 2][row] = va.z; As[sc + 3][row] = va.w;
            const float4 vb = *(const float4*)(w + (size_t)(n0 + row) * K_IN + kt + sc);
            Bs2[sc + 0][row] = vb.x; Bs2[sc + 1][row] = vb.y;
            Bs2[sc + 2][row] = vb.z; Bs2[sc + 3][row] = vb.w;
        }
        __syncthreads();
#pragma unroll
        for (int kk = 0; kk < 32; ++kk) {
            const float4 a0 = *(const float4*)&As[kk][ty * 8];
            const float4 a1 = *(const float4*)&As[kk][ty * 8 + 4];
            const float4 b0 = *(const float4*)&Bs2[kk][tx * 8];
            const float4 b1 = *(const float4*)&Bs2[kk][tx * 8 + 4];
            const float a[8] = {a0.x, a0.y, a0.z, a0.w, a1.x, a1.y, a1.z, a1.w};
            const float b[8] = {b0.x, b0.y, b0.z, b0.w, b1.x, b1.y, b1.z, b1.w};
#pragma unroll
            for (int i = 0; i < 8; ++i)
#pragma unroll
                for (int j = 0; j < 8; ++j)
                    acc[i][j] = fmaf(a[i], b[j], acc[i][j]);
        }
    }
    const int nb = n0 + tx * 8;
    float bv[8], sv[8];
#pragma unroll
    for (int j = 0; j < 8; ++j) { bv[j] = bias[nb + j]; sv[j] = sign[nb + j]; }
#pragma unroll
    for (int i = 0; i < 8; ++i) {
        const int m = m0 + ty * 8 + i;
        float o[8];
#pragma unroll
        for (int j = 0; j < 8; ++j) {
            const float t = (acc[i][j] + bv[j]) * sv[j];
            if (fabsf(t + 0.5f) < TAU) {
                const float cs = c3_score(x + (size_t)m * K_IN,
                                          w + (size_t)(nb + j) * K_IN);
                o[j] = (((cs + bv[j]) * sv[j]) >= -0.5f) ? 1.0f : 0.0f;
            } else {
                o[j] = (t >= -0.5f) ? 1.0f : 0.0f;
            }
        }
        float4* op = (float4*)(out + (size_t)m * N_OUT + nb);
        op[0] = make_float4(o[0], o[1], o[2], o[3]);
        op[1] = make_float4(o[4], o[5], o[6], o[7]);
    }
}

extern "C" void kernel_launch(void* const* d_in, const int* in_sizes, int n_in,
                              void* d_out, int out_size, void* d_ws, size_t ws_size,
                              hipStream_t stream) {
    const float* x    = (const float*)d_in[0];
    const float* w    = (const float*)d_in[1];
    const float* bias = (const float*)d_in[2];
    const float* sign = (const float*)d_in[3];

    if (n_in >= 4 && in_sizes[0] != M_BATCH * K_IN) {   // defensive no-op
        const float* small[2] = {nullptr, nullptr};
        int nsmall = 0;
        for (int i = 0; i < 4; ++i) {
            if (in_sizes[i] == M_BATCH * K_IN)      x = (const float*)d_in[i];
            else if (in_sizes[i] == N_OUT * K_IN)   w = (const float*)d_in[i];
            else if (nsmall < 2) small[nsmall++] = (const float*)d_in[i];
        }
        if (nsmall == 2) { bias = small[0]; sign = small[1]; }
    }

    float* out = (float*)d_out;

    if (ws_size >= WS_NEED) {
        short*    wtp = (short*)d_ws;
        unsigned* cnt = (unsigned*)((char*)d_ws + CNT_BOFF);
        unsigned* wl  = (unsigned*)((char*)d_ws + WL_BOFF);

        wconv22<<<128, 512, 0, stream>>>(w, wtp, cnt);
        binlin_db22<<<1024, 256, 0, stream>>>(x, w, wtp, bias, sign, out, cnt, wl);
        fixwl22<<<256, 256, 0, stream>>>(x, w, bias, sign, cnt, wl, out);
    } else {
        dim3 grid(N_OUT / 128, M_BATCH / 128);
        binlin_fast<<<grid, 256, 0, stream>>>(x, w, bias, sign, out);
    }
}